// Round 10
// baseline (107.782 us; speedup 1.0000x reference)
//
#include <hip/hip_runtime.h>

// Involution: B=4, C=256, H=W=56, K=7, GC=16 -> G=16, Cr=64, K2=49
// R10: SINGLE kernel, grid 392 = (49 tiles x 2 group-halves x 4 b), 512 thr.
//     conv1 per tile (2x redundancy), then 4 iterations x TWO concurrent
//     groups (wave-set hs owns g = gh*8 + 2*gi + hs). 2 blocks/CU co-resident
//     (VGPR<=128 via launch_bounds, LDS 54 KB) -> inter-block TLP hides
//     barrier stalls; all 256 CUs busy. XCD chunking exact: 392 = 8*49,
//     each XCD = one (b,gh) panel x 49 tiles (~3.2 MB unique < 4 MB L2).
// LDS map (bytes), total 54048:
//   [0, 9216)       bufA [64px][72] f16  - conv1 staging
//   [0, 8960)       lxh0 [16ch][14][20] f16 - overlays bufA after conv1
//   [9216, 18432)   lmid [64px][72] f16  - conv1 out tile (read-only shared)
//   [18432, 31760)  lw2[0] [49][68] f32  - set-0 weights
//   [31760, 45088)  lw2[1] [49][68] f32  - set-1 weights
//   [45088, 54048)  lxh1 [16ch][14][20] f16 - set-1 halo
// ws unused.

#define EPS 1e-5f

typedef __fp16 half2t __attribute__((ext_vector_type(2)));
typedef __fp16 half4t __attribute__((ext_vector_type(4)));
typedef __fp16 half8t __attribute__((ext_vector_type(8)));
typedef float floatx4 __attribute__((ext_vector_type(4)));

__device__ inline half8t pack8(float4 u0, float4 u1, float s) {
    half8t a;
    half2t q;
    q = __builtin_amdgcn_cvt_pkrtz(u0.x * s, u0.y * s); a[0] = q[0]; a[1] = q[1];
    q = __builtin_amdgcn_cvt_pkrtz(u0.z * s, u0.w * s); a[2] = q[0]; a[3] = q[1];
    q = __builtin_amdgcn_cvt_pkrtz(u1.x * s, u1.y * s); a[4] = q[0]; a[5] = q[1];
    q = __builtin_amdgcn_cvt_pkrtz(u1.z * s, u1.w * s); a[6] = q[0]; a[7] = q[1];
    return a;
}

__global__ __launch_bounds__(512, 4) void k_fused(
    const float* __restrict__ x, const float* __restrict__ w1,
    const float* __restrict__ gamma, const float* __restrict__ beta,
    const float* __restrict__ mean, const float* __restrict__ var,
    const float* __restrict__ cw, const float* __restrict__ cb,
    float* __restrict__ out)
{
    __shared__ __align__(16) unsigned char smem[54048];
    __fp16* bufA = (__fp16*)smem;
    __fp16* lmid = (__fp16*)(smem + 9216);

    const int t = threadIdx.x;
    // ---- exact XCD chunking: 392 = 8 XCDs x 49; XCD owns one (b,gh) panel
    const int id  = blockIdx.x;
    const int xcd = id & 7, lid = id >> 3;
    const int wg  = xcd * 49 + lid;
    const int b    = wg / 98;
    const int gh   = (wg / 49) & 1;              // group-half: groups gh*8..gh*8+7
    const int tile = wg % 49;
    const int th = tile / 7, tw = tile % 7;
    const int h0 = th * 8, w0 = tw * 8;
    const int lane = t & 63, wvid = t >> 6;
    const int mrow = lane & 15, quad = lane >> 4;

    // ---------------- conv1: 8-wave split (o-strip ow, px-half ph) ---------
    const int ow = wvid & 3, ph = wvid >> 2;
    const int orow = ow * 16 + mrow;
    const float s1 = gamma[orow] * rsqrtf(var[orow] + EPS);

    half8t A[4][2];
#pragma unroll
    for (int ch = 0; ch < 4; ++ch)
#pragma unroll
        for (int h = 0; h < 2; ++h) {
            const float* src = &w1[orow * 256 + ch * 64 + h * 32 + quad * 8];
            A[ch][h] = pack8(*(const float4*)src, *(const float4*)(src + 4), s1);
        }

    // staging map: ch-pair c2 0..31, pq 0..15 -> row = pq>>1, col-half ch4
    const int c2 = t & 31, pq = t >> 5;
    const int srow = pq >> 1, ch4 = (pq & 1) * 4;
    const float* xbase = &x[(size_t)(b * 256 + 2 * c2) * 3136 +
                            (h0 + srow) * 56 + w0 + ch4];

    float4 ca = *(const float4*)xbase;
    float4 cbv = *(const float4*)(xbase + 3136);

    floatx4 acc1[2] = {};
#pragma unroll
    for (int ch = 0; ch < 4; ++ch) {
        float4 na, nb;
        if (ch < 3) {
            const float* rn = xbase + (size_t)(ch + 1) * 64 * 3136;
            na = *(const float4*)rn;
            nb = *(const float4*)(rn + 3136);
        }
        const float* fa = (const float*)&ca;
        const float* fb = (const float*)&cbv;
#pragma unroll
        for (int j = 0; j < 4; ++j) {
            half2t q = __builtin_amdgcn_cvt_pkrtz(fa[j], fb[j]);
            *(half2t*)&bufA[(srow * 8 + ch4 + j) * 72 + 2 * c2] = q;
        }
        __syncthreads();
#pragma unroll
        for (int p2 = 0; p2 < 2; ++p2) {
            int pt = ph * 2 + p2;
            half8t bf0 = *(const half8t*)&bufA[(pt * 16 + mrow) * 72 + quad * 8];
            half8t bf1 = *(const half8t*)&bufA[(pt * 16 + mrow) * 72 + quad * 8 + 32];
            acc1[p2] = __builtin_amdgcn_mfma_f32_16x16x32_f16(A[ch][0], bf0, acc1[p2], 0, 0, 0);
            acc1[p2] = __builtin_amdgcn_mfma_f32_16x16x32_f16(A[ch][1], bf1, acc1[p2], 0, 0, 0);
        }
        __syncthreads();
        ca = na; cbv = nb;
    }

    // conv1 epilogue: bias + relu -> lmid [px][c] f16 (stride 72)
    {
        float bb[4];
#pragma unroll
        for (int i = 0; i < 4; ++i) {
            int o = ow * 16 + quad * 4 + i;
            float so = gamma[o] * rsqrtf(var[o] + EPS);
            bb[i] = beta[o] - mean[o] * so;
        }
#pragma unroll
        for (int p2 = 0; p2 < 2; ++p2)
#pragma unroll
            for (int i = 0; i < 4; ++i) {
                float v = fmaxf(acc1[p2][i] + bb[i], 0.f);
                lmid[((ph * 2 + p2) * 16 + mrow) * 72 + ow * 16 + quad * 4 + i] = (__fp16)v;
            }
    }
    __syncthreads();   // lmid ready; bufA dead -> lxh0 region free

    // ---------------- group loop: 4 iterations, 2 concurrent wave-sets -----
    const int hs = wvid >> 2;          // wave-set: handles g = gh*8 + 2*gi + hs
    const int wl = wvid & 3;           // local wave in set
    const int tl = t & 255;            // local thread in set
    __fp16* myxh = (hs == 0) ? (__fp16*)smem : (__fp16*)(smem + 45088);
    float*  mylw = (float*)(smem + 18432 + hs * 13328);
    const int krow = wl * 16 + mrow;
    const int g0 = gh * 8;

    // prefetch g = g0 + hs: halo + cw
    float4 rv4[4];
    int    rslot[4];
#pragma unroll
    for (int i = 0; i < 4; ++i) {
        int s = tl + i * 256;
        rslot[i] = s;
        float4 v = make_float4(0.f, 0.f, 0.f, 0.f);
        if (s < 896) {
            int chh = s / 56, r = s % 56;
            int row = r >> 2, q = r & 3;
            int ghr = h0 + row - 3;
            int gwb = w0 - 4 + q * 4;
            bool ok = (ghr >= 0) & (ghr < 56) & (gwb >= 0) & (gwb <= 52);
            int ghc = min(max(ghr, 0), 55);
            int gwc = min(max(gwb, 0), 52);
            float4 ld = *(const float4*)&x[(size_t)(b * 256 + (g0 + hs) * 16 + chh) * 3136 +
                                           ghc * 56 + gwc];
            if (ok) v = ld;
        }
        rv4[i] = v;
    }
    float4 rcw0 = make_float4(0,0,0,0), rcw1 = rcw0, rcw2 = rcw0, rcw3 = rcw0;
    if (krow < 49) {
        const float* src = &cw[(size_t)((g0 + hs) * 49 + krow) * 64 + quad * 8];
        rcw0 = *(const float4*)src;        rcw1 = *(const float4*)(src + 4);
        rcw2 = *(const float4*)(src + 32); rcw3 = *(const float4*)(src + 36);
    }

#pragma unroll 1
    for (int gi = 0; gi < 4; ++gi) {
        const int g = g0 + gi * 2 + hs;

        half8t a0 = pack8(rcw0, rcw1, 1.f);
        half8t a1 = pack8(rcw2, rcw3, 1.f);
        if (krow >= 49) { a0 = half8t{}; a1 = half8t{}; }

        // GEMM: D[49 ko x 64 px] = W_g[49 x 64c] * M[64c x 64px] (per set)
        {
            float bias[4];
            int   kor[4];
#pragma unroll
            for (int i = 0; i < 4; ++i) {
                kor[i]  = wl * 16 + quad * 4 + i;
                bias[i] = (kor[i] < 49) ? cb[g * 49 + kor[i]] : 0.f;
            }
#pragma unroll
            for (int pt = 0; pt < 4; ++pt) {
                half8t b0 = *(const half8t*)&lmid[(pt * 16 + mrow) * 72 + quad * 8];
                half8t b1 = *(const half8t*)&lmid[(pt * 16 + mrow) * 72 + quad * 8 + 32];
                floatx4 acc = {0.f, 0.f, 0.f, 0.f};
                acc = __builtin_amdgcn_mfma_f32_16x16x32_f16(a0, b0, acc, 0, 0, 0);
                acc = __builtin_amdgcn_mfma_f32_16x16x32_f16(a1, b1, acc, 0, 0, 0);
#pragma unroll
                for (int i = 0; i < 4; ++i)
                    if (kor[i] < 49)
                        mylw[kor[i] * 68 + pt * 16 + mrow] = acc[i] + bias[i];
            }
        }

        // halo regs -> myxh f16 [ch][row][20] (ch stride 280 halves)
#pragma unroll
        for (int i = 0; i < 4; ++i) {
            int s = rslot[i];
            if (s < 896) {
                int chh = s / 56, r = s % 56;
                int row = r >> 2, q = r & 3;
                half2t p0 = __builtin_amdgcn_cvt_pkrtz(rv4[i].x, rv4[i].y);
                half2t p1 = __builtin_amdgcn_cvt_pkrtz(rv4[i].z, rv4[i].w);
                half4t hv; hv[0] = p0[0]; hv[1] = p0[1]; hv[2] = p1[0]; hv[3] = p1[1];
                *(half4t*)&myxh[chh * 280 + row * 20 + q * 4] = hv;
            }
        }

        // prefetch next group's halo + cw (g+2)
        if (gi < 3) {
#pragma unroll
            for (int i = 0; i < 4; ++i) {
                int s = rslot[i];
                float4 v = make_float4(0.f, 0.f, 0.f, 0.f);
                if (s < 896) {
                    int chh = s / 56, r = s % 56;
                    int row = r >> 2, q = r & 3;
                    int ghr = h0 + row - 3;
                    int gwb = w0 - 4 + q * 4;
                    bool ok = (ghr >= 0) & (ghr < 56) & (gwb >= 0) & (gwb <= 52);
                    int ghc = min(max(ghr, 0), 55);
                    int gwc = min(max(gwb, 0), 52);
                    float4 ld = *(const float4*)&x[(size_t)(b * 256 + (g + 2) * 16 + chh) * 3136 +
                                                   ghc * 56 + gwc];
                    if (ok) v = ld;
                }
                rv4[i] = v;
            }
            if (krow < 49) {
                const float* src = &cw[(size_t)((g + 2) * 49 + krow) * 64 + quad * 8];
                rcw0 = *(const float4*)src;        rcw1 = *(const float4*)(src + 4);
                rcw2 = *(const float4*)(src + 32); rcw3 = *(const float4*)(src + 36);
            }
        }
        __syncthreads();   // lw2 + lxh ready (both sets)

        // apply: per set, thread = (cc = tl>>4 ch, 4 px); f16 x, f32 accum
        {
            const int cc = tl >> 4, pxt = tl & 15;
            const int sh = pxt >> 1, sw4 = (pxt & 1) * 4;
            float a0f = 0.f, a1f = 0.f, a2f = 0.f, a3f = 0.f;
#pragma unroll
            for (int kh = 0; kh < 7; ++kh) {
                const int rbh = cc * 280 + (sh + kh) * 20 + sw4;
                half4t f0 = *(const half4t*)&myxh[rbh];
                half4t f1 = *(const half4t*)&myxh[rbh + 4];
                half4t f2 = *(const half4t*)&myxh[rbh + 8];
                float xw[12];
#pragma unroll
                for (int j = 0; j < 4; ++j) {
                    xw[j]     = (float)f0[j];
                    xw[j + 4] = (float)f1[j];
                    xw[j + 8] = (float)f2[j];
                }
#pragma unroll
                for (int kw = 0; kw < 7; ++kw) {
                    const float4 wv = *(const float4*)&mylw[(kh * 7 + kw) * 68 + pxt * 4];
                    a0f = fmaf(wv.x, xw[kw + 1], a0f);
                    a1f = fmaf(wv.y, xw[kw + 2], a1f);
                    a2f = fmaf(wv.z, xw[kw + 3], a2f);
                    a3f = fmaf(wv.w, xw[kw + 4], a3f);
                }
            }
            *(float4*)&out[(size_t)(b * 256 + g * 16 + cc) * 3136 +
                           (h0 + sh) * 56 + w0 + sw4] =
                make_float4(a0f, a1f, a2f, a3f);
        }
        __syncthreads();   // buffers consumed; next gi may overwrite
    }
}

extern "C" void kernel_launch(void* const* d_in, const int* in_sizes, int n_in,
                              void* d_out, int out_size, void* d_ws, size_t ws_size,
                              hipStream_t stream) {
    const float* x     = (const float*)d_in[0];
    const float* w1    = (const float*)d_in[1];
    const float* gamma = (const float*)d_in[2];
    const float* beta  = (const float*)d_in[3];
    const float* mean  = (const float*)d_in[4];
    const float* var   = (const float*)d_in[5];
    const float* cw    = (const float*)d_in[6];
    const float* cb    = (const float*)d_in[7];
    float* out = (float*)d_out;

    (void)d_ws; (void)ws_size;

    k_fused<<<dim3(392), 512, 0, stream>>>(x, w1, gamma, beta, mean, var,
                                           cw, cb, out);
}

// Round 11
// 107.311 us; speedup vs baseline: 1.0044x; 1.0044x over previous
//
#include <hip/hip_runtime.h>

// Involution: B=4, C=256, H=W=56, K=7, GC=16 -> G=16, Cr=64, K2=49
// R11: R7 base (best measured, 105.3us) + ONE change: generated weights
//      lw2 stored f16 (GEMM epilogue cvt, apply reads b64 instead of b128)
//      -> halves the dominant per-CU LDS data-cycle term in apply.
//      (R9==R10 null isolated LDS issue/data throughput as k2's binding
//      resource; f16 products already flow through f16 MFMA, R1/R2 passed
//      with f16 lw2 at identical absmax.)
// ws: mid f16 [4][3136 px][64 c] @0 (1605632 B).

#define EPS 1e-5f

typedef __fp16 half2t __attribute__((ext_vector_type(2)));
typedef __fp16 half4t __attribute__((ext_vector_type(4)));
typedef __fp16 half8t __attribute__((ext_vector_type(8)));
typedef float floatx4 __attribute__((ext_vector_type(4)));

__device__ inline half8t pack8(float4 u0, float4 u1, float s) {
    half8t a;
    half2t q;
    q = __builtin_amdgcn_cvt_pkrtz(u0.x * s, u0.y * s); a[0] = q[0]; a[1] = q[1];
    q = __builtin_amdgcn_cvt_pkrtz(u0.z * s, u0.w * s); a[2] = q[0]; a[3] = q[1];
    q = __builtin_amdgcn_cvt_pkrtz(u1.x * s, u1.y * s); a[4] = q[0]; a[5] = q[1];
    q = __builtin_amdgcn_cvt_pkrtz(u1.z * s, u1.w * s); a[6] = q[0]; a[7] = q[1];
    return a;
}

// ---------------- Kernel 1: conv1 (1x1, 256->64) + BN + ReLU, MFMA ----------
// grid (98,4): block 64o x 32px. All chunk loads pipelined up front.
__global__ __launch_bounds__(256, 4) void k1_conv1(
    const float* __restrict__ x, const float* __restrict__ w1,
    const float* __restrict__ gamma, const float* __restrict__ beta,
    const float* __restrict__ mean, const float* __restrict__ var,
    __fp16* __restrict__ mid)
{
    __shared__ __align__(16) __fp16 lxB[4 * 32 * 72];  // [chunk][px][72]
    const int t    = threadIdx.x;
    const int b    = blockIdx.y;
    const int p0   = blockIdx.x * 32;
    const int lane = t & 63, wvid = t >> 6;
    const int mrow = lane & 15, quad = lane >> 4;

    // ---- staging loads FIRST: 4 chunks x 2 ch-rows x 4 px, all in flight ----
    const int c2 = t & 31, pxq = t >> 5;             // ch-pair, px-quad
    float4 ra[4], rb[4];
#pragma unroll
    for (int ch = 0; ch < 4; ++ch) {
        const float* r0 = &x[(size_t)(b * 256 + ch * 64 + 2 * c2) * 3136 + p0 + pxq * 4];
        ra[ch] = *(const float4*)r0;
        rb[ch] = *(const float4*)(r0 + 3136);
    }

    // ---- A-fragments meanwhile: BN scale folded, f32 -> f16 (w1 L2-hot) ----
    const int orow = wvid * 16 + mrow;
    const float s = gamma[orow] * rsqrtf(var[orow] + EPS);
    half8t A[4][2];
#pragma unroll
    for (int ch = 0; ch < 4; ++ch)
#pragma unroll
        for (int h = 0; h < 2; ++h) {
            const float* src = &w1[orow * 256 + ch * 64 + h * 32 + quad * 8];
            A[ch][h] = pack8(*(const float4*)src, *(const float4*)(src + 4), s);
        }

    // ---- write all chunks to LDS (cvt to f16), one barrier ----
#pragma unroll
    for (int ch = 0; ch < 4; ++ch) {
        const float* f0 = (const float*)&ra[ch];
        const float* f1 = (const float*)&rb[ch];
#pragma unroll
        for (int j = 0; j < 4; ++j) {
            half2t q = __builtin_amdgcn_cvt_pkrtz(f0[j], f1[j]);
            *(half2t*)&lxB[ch * 2304 + (pxq * 4 + j) * 72 + 2 * c2] = q;
        }
    }
    __syncthreads();

    // ---- MFMA: 16 per wave, no intervening barriers ----
    floatx4 acc[2] = {};
#pragma unroll
    for (int ch = 0; ch < 4; ++ch)
#pragma unroll
        for (int pt = 0; pt < 2; ++pt) {
            half8t bf0 = *(const half8t*)&lxB[ch * 2304 + (pt * 16 + mrow) * 72 + quad * 8];
            half8t bf1 = *(const half8t*)&lxB[ch * 2304 + (pt * 16 + mrow) * 72 + quad * 8 + 32];
            acc[pt] = __builtin_amdgcn_mfma_f32_16x16x32_f16(A[ch][0], bf0, acc[pt], 0, 0, 0);
            acc[pt] = __builtin_amdgcn_mfma_f32_16x16x32_f16(A[ch][1], bf1, acc[pt], 0, 0, 0);
        }
    __syncthreads();

    // ---- epilogue: bias + relu -> f16, transpose via lxB, b128 out ----
    float bb[4];
#pragma unroll
    for (int i = 0; i < 4; ++i) {
        int o = wvid * 16 + quad * 4 + i;
        float so = gamma[o] * rsqrtf(var[o] + EPS);
        bb[i] = beta[o] - mean[o] * so;
    }
#pragma unroll
    for (int pt = 0; pt < 2; ++pt)
#pragma unroll
        for (int i = 0; i < 4; ++i) {
            float v = fmaxf(acc[pt][i] + bb[i], 0.f);
            lxB[(pt * 16 + mrow) * 72 + wvid * 16 + quad * 4 + i] = (__fp16)v;
        }
    __syncthreads();
    {
        int px = t >> 3, o8 = t & 7;                 // 256 slots = 32px x 8
        *(half8t*)&mid[(size_t)(b * 3136 + p0 + px) * 64 + o8 * 8] =
            *(const half8t*)&lxB[px * 72 + o8 * 8];
    }
}

// ---------------- Kernel 2: fused conv2 (f16 MFMA) + unfold/apply -----------
// grid: 3136 linear blocks, XCD-chunked swizzle.
// LDS map (bytes):
//   [0, 9216)      lmid [64px][72] f16      (GEMM phase only)
//   [0, 15616)     lx   [16ch][244] f32     (halo, overlays lmid AFTER GEMM)
//   [15616, 22280) lw2h [49][68] f16        (generated weights, f16)
__global__ __launch_bounds__(256, 5) void k23_fused(
    const float* __restrict__ x, const __fp16* __restrict__ mid,
    const float* __restrict__ cw, const float* __restrict__ cb,
    float* __restrict__ out)
{
    __shared__ __align__(16) unsigned char smem[22280];
    __fp16* lmid = (__fp16*)smem;
    float*  lx   = (float*)smem;                 // ch stride 244, row stride 17
    __fp16* lw2h = (__fp16*)(smem + 15616);      // [49][68] f16

    const int t  = threadIdx.x;
    // ---- XCD-chunked bijective swizzle: 3136 = 8 XCDs x 392 slots.
    const int id   = blockIdx.x;
    const int wg   = (id & 7) * 392 + (id >> 3);
    const int tile = wg % 49;
    const int pg   = wg / 49;                    // pg = b*16 + g
    const int g    = pg & 15;
    const int b    = pg >> 4;
    const int th = tile / 7, tw = tile % 7;
    const int h0 = th * 8, w0 = tw * 8;
    const int lane = t & 63, wvid = t >> 6;
    const int mrow = lane & 15, quad = lane >> 4;

    // ---- halo prefetch FIRST: 16ch x 14rows x 4 f4 (cols w0-4..w0+11) ----
    float4 rv4[4];
    int    rslot[4];
#pragma unroll
    for (int i = 0; i < 4; ++i) {
        int s = t + i * 256;
        rslot[i] = s;
        float4 v = make_float4(0.f, 0.f, 0.f, 0.f);
        if (s < 896) {
            int ch = s / 56, r = s % 56;
            int row = r >> 2, q = r & 3;
            int gh = h0 + row - 3;
            int gwb = w0 - 4 + q * 4;
            bool ok = (gh >= 0) & (gh < 56) & (gwb >= 0) & (gwb <= 52);
            int ghc = min(max(gh, 0), 55);
            int gwc = min(max(gwb, 0), 52);
            float4 ld = *(const float4*)&x[(size_t)(b * 256 + g * 16 + ch) * 3136 +
                                           ghc * 56 + gwc];
            if (ok) v = ld;
        }
        rv4[i] = v;
    }

    // A-fragments: cw f32 -> f16 inline (L2-hot); rows >=49 are zero
    const int krow = wvid * 16 + mrow;
    half8t a0 = {}, a1 = {};
    if (krow < 49) {
        const float* src = &cw[(size_t)(g * 49 + krow) * 64 + quad * 8];
        a0 = pack8(*(const float4*)src,        *(const float4*)(src + 4),  1.f);
        a1 = pack8(*(const float4*)(src + 32), *(const float4*)(src + 36), 1.f);
    }

    // stage lmid [px][c] (stride 72): contiguous-slot b128 copies
#pragma unroll
    for (int i = 0; i < 2; ++i) {
        int s  = t + i * 256;
        int px = s >> 3, c8 = s & 7;
        int pix = (h0 + (px >> 3)) * 56 + w0 + (px & 7);
        *(half8t*)&lmid[px * 72 + c8 * 8] =
            *(const half8t*)&mid[(size_t)(b * 3136 + pix) * 64 + c8 * 8];
    }
    __syncthreads();

    // MFMA GEMM: D[ko][px] = sum_c W[ko][c] * M[c][px] -> lw2h f16
    {
        float bias[4];
        int   kor[4];
#pragma unroll
        for (int i = 0; i < 4; ++i) {
            kor[i]  = wvid * 16 + quad * 4 + i;
            bias[i] = (kor[i] < 49) ? cb[g * 49 + kor[i]] : 0.f;
        }
#pragma unroll
        for (int pt = 0; pt < 4; ++pt) {
            half8t b0 = *(const half8t*)&lmid[(pt * 16 + mrow) * 72 + quad * 8];
            half8t b1 = *(const half8t*)&lmid[(pt * 16 + mrow) * 72 + quad * 8 + 32];
            floatx4 acc = {0.f, 0.f, 0.f, 0.f};
            acc = __builtin_amdgcn_mfma_f32_16x16x32_f16(a0, b0, acc, 0, 0, 0);
            acc = __builtin_amdgcn_mfma_f32_16x16x32_f16(a1, b1, acc, 0, 0, 0);
#pragma unroll
            for (int i = 0; i < 4; ++i)
                if (kor[i] < 49)
                    lw2h[kor[i] * 68 + pt * 16 + mrow] = (__fp16)(acc[i] + bias[i]);
        }
    }
    __syncthreads();

    // halo f4 regs -> LDS as 4x b32 (ch stride 244, row stride 17, 16 cols)
#pragma unroll
    for (int i = 0; i < 4; ++i) {
        int s = rslot[i];
        if (s < 896) {
            int ch = s / 56, r = s % 56;
            int row = r >> 2, q = r & 3;
            float* dst = &lx[ch * 244 + row * 17 + q * 4];
            dst[0] = rv4[i].x; dst[1] = rv4[i].y;
            dst[2] = rv4[i].z; dst[3] = rv4[i].w;
        }
    }
    __syncthreads();

    // apply: thread = (cc = t>>4, 4 consecutive out px); f16 weight b64 reads
    const int cc = t >> 4, pxt = t & 15;
    const int sh = pxt >> 1, sw4 = (pxt & 1) * 4;
    float a0f = 0.f, a1f = 0.f, a2f = 0.f, a3f = 0.f;
#pragma unroll
    for (int kh = 0; kh < 7; ++kh) {
        float xr[10];
        const int base = cc * 244 + (sh + kh) * 17 + sw4 + 1;
#pragma unroll
        for (int j = 0; j < 10; ++j) xr[j] = lx[base + j];
#pragma unroll
        for (int kw = 0; kw < 7; ++kw) {
            half4t wq = *(const half4t*)&lw2h[(kh * 7 + kw) * 68 + pxt * 4];
            a0f = fmaf((float)wq[0], xr[kw + 0], a0f);
            a1f = fmaf((float)wq[1], xr[kw + 1], a1f);
            a2f = fmaf((float)wq[2], xr[kw + 2], a2f);
            a3f = fmaf((float)wq[3], xr[kw + 3], a3f);
        }
    }
    *(float4*)&out[(size_t)(b * 256 + g * 16 + cc) * 3136 + (h0 + sh) * 56 + w0 + sw4] =
        make_float4(a0f, a1f, a2f, a3f);
}

extern "C" void kernel_launch(void* const* d_in, const int* in_sizes, int n_in,
                              void* d_out, int out_size, void* d_ws, size_t ws_size,
                              hipStream_t stream) {
    const float* x     = (const float*)d_in[0];
    const float* w1    = (const float*)d_in[1];
    const float* gamma = (const float*)d_in[2];
    const float* beta  = (const float*)d_in[3];
    const float* mean  = (const float*)d_in[4];
    const float* var   = (const float*)d_in[5];
    const float* cw    = (const float*)d_in[6];
    const float* cb    = (const float*)d_in[7];
    float* out = (float*)d_out;

    __fp16* mid = (__fp16*)d_ws;             // 1605632 B

    k1_conv1<<<dim3(98, 4), 256, 0, stream>>>(x, w1, gamma, beta, mean, var, mid);
    k23_fused<<<dim3(3136), 256, 0, stream>>>(x, mid, cw, cb, out);
}

// Round 12
// 102.737 us; speedup vs baseline: 1.0491x; 1.0445x over previous
//
#include <hip/hip_runtime.h>

// Involution: B=4, C=256, H=W=56, K=7, GC=16 -> G=16, Cr=64, K2=49
// R12: R11 base + ONE change: k2 halo stored f16 [16ch][14][20] (R6-verified
//      layout), apply reads 3x half4 per kh instead of 10x b32 -> apply LDS
//      instruction count 119 -> 70 per wave (issue-bound term halved).
//      LDS 22280 -> 15880 B.
// ws: mid f16 [4][3136 px][64 c] @0 (1605632 B).

#define EPS 1e-5f

typedef __fp16 half2t __attribute__((ext_vector_type(2)));
typedef __fp16 half4t __attribute__((ext_vector_type(4)));
typedef __fp16 half8t __attribute__((ext_vector_type(8)));
typedef float floatx4 __attribute__((ext_vector_type(4)));

__device__ inline half8t pack8(float4 u0, float4 u1, float s) {
    half8t a;
    half2t q;
    q = __builtin_amdgcn_cvt_pkrtz(u0.x * s, u0.y * s); a[0] = q[0]; a[1] = q[1];
    q = __builtin_amdgcn_cvt_pkrtz(u0.z * s, u0.w * s); a[2] = q[0]; a[3] = q[1];
    q = __builtin_amdgcn_cvt_pkrtz(u1.x * s, u1.y * s); a[4] = q[0]; a[5] = q[1];
    q = __builtin_amdgcn_cvt_pkrtz(u1.z * s, u1.w * s); a[6] = q[0]; a[7] = q[1];
    return a;
}

// ---------------- Kernel 1: conv1 (1x1, 256->64) + BN + ReLU, MFMA ----------
// grid (98,4): block 64o x 32px. All chunk loads pipelined up front.
__global__ __launch_bounds__(256, 4) void k1_conv1(
    const float* __restrict__ x, const float* __restrict__ w1,
    const float* __restrict__ gamma, const float* __restrict__ beta,
    const float* __restrict__ mean, const float* __restrict__ var,
    __fp16* __restrict__ mid)
{
    __shared__ __align__(16) __fp16 lxB[4 * 32 * 72];  // [chunk][px][72]
    const int t    = threadIdx.x;
    const int b    = blockIdx.y;
    const int p0   = blockIdx.x * 32;
    const int lane = t & 63, wvid = t >> 6;
    const int mrow = lane & 15, quad = lane >> 4;

    // ---- staging loads FIRST: 4 chunks x 2 ch-rows x 4 px, all in flight ----
    const int c2 = t & 31, pxq = t >> 5;             // ch-pair, px-quad
    float4 ra[4], rb[4];
#pragma unroll
    for (int ch = 0; ch < 4; ++ch) {
        const float* r0 = &x[(size_t)(b * 256 + ch * 64 + 2 * c2) * 3136 + p0 + pxq * 4];
        ra[ch] = *(const float4*)r0;
        rb[ch] = *(const float4*)(r0 + 3136);
    }

    // ---- A-fragments meanwhile: BN scale folded, f32 -> f16 (w1 L2-hot) ----
    const int orow = wvid * 16 + mrow;
    const float s = gamma[orow] * rsqrtf(var[orow] + EPS);
    half8t A[4][2];
#pragma unroll
    for (int ch = 0; ch < 4; ++ch)
#pragma unroll
        for (int h = 0; h < 2; ++h) {
            const float* src = &w1[orow * 256 + ch * 64 + h * 32 + quad * 8];
            A[ch][h] = pack8(*(const float4*)src, *(const float4*)(src + 4), s);
        }

    // ---- write all chunks to LDS (cvt to f16), one barrier ----
#pragma unroll
    for (int ch = 0; ch < 4; ++ch) {
        const float* f0 = (const float*)&ra[ch];
        const float* f1 = (const float*)&rb[ch];
#pragma unroll
        for (int j = 0; j < 4; ++j) {
            half2t q = __builtin_amdgcn_cvt_pkrtz(f0[j], f1[j]);
            *(half2t*)&lxB[ch * 2304 + (pxq * 4 + j) * 72 + 2 * c2] = q;
        }
    }
    __syncthreads();

    // ---- MFMA: 16 per wave, no intervening barriers ----
    floatx4 acc[2] = {};
#pragma unroll
    for (int ch = 0; ch < 4; ++ch)
#pragma unroll
        for (int pt = 0; pt < 2; ++pt) {
            half8t bf0 = *(const half8t*)&lxB[ch * 2304 + (pt * 16 + mrow) * 72 + quad * 8];
            half8t bf1 = *(const half8t*)&lxB[ch * 2304 + (pt * 16 + mrow) * 72 + quad * 8 + 32];
            acc[pt] = __builtin_amdgcn_mfma_f32_16x16x32_f16(A[ch][0], bf0, acc[pt], 0, 0, 0);
            acc[pt] = __builtin_amdgcn_mfma_f32_16x16x32_f16(A[ch][1], bf1, acc[pt], 0, 0, 0);
        }
    __syncthreads();

    // ---- epilogue: bias + relu -> f16, transpose via lxB, b128 out ----
    float bb[4];
#pragma unroll
    for (int i = 0; i < 4; ++i) {
        int o = wvid * 16 + quad * 4 + i;
        float so = gamma[o] * rsqrtf(var[o] + EPS);
        bb[i] = beta[o] - mean[o] * so;
    }
#pragma unroll
    for (int pt = 0; pt < 2; ++pt)
#pragma unroll
        for (int i = 0; i < 4; ++i) {
            float v = fmaxf(acc[pt][i] + bb[i], 0.f);
            lxB[(pt * 16 + mrow) * 72 + wvid * 16 + quad * 4 + i] = (__fp16)v;
        }
    __syncthreads();
    {
        int px = t >> 3, o8 = t & 7;                 // 256 slots = 32px x 8
        *(half8t*)&mid[(size_t)(b * 3136 + p0 + px) * 64 + o8 * 8] =
            *(const half8t*)&lxB[px * 72 + o8 * 8];
    }
}

// ---------------- Kernel 2: fused conv2 (f16 MFMA) + unfold/apply -----------
// grid: 3136 linear blocks, XCD-chunked swizzle.
// LDS map (bytes):
//   [0, 9216)      lmid [64px][72] f16        (GEMM phase only)
//   [0, 8960)      lxh  [16ch][14][20] f16    (halo, overlays lmid AFTER GEMM)
//   [9216, 15880)  lw2h [49][68] f16          (generated weights, f16)
__global__ __launch_bounds__(256, 5) void k23_fused(
    const float* __restrict__ x, const __fp16* __restrict__ mid,
    const float* __restrict__ cw, const float* __restrict__ cb,
    float* __restrict__ out)
{
    __shared__ __align__(16) unsigned char smem[15880];
    __fp16* lmid = (__fp16*)smem;
    __fp16* lxh  = (__fp16*)smem;                // ch stride 280, row stride 20
    __fp16* lw2h = (__fp16*)(smem + 9216);       // [49][68] f16

    const int t  = threadIdx.x;
    // ---- XCD-chunked bijective swizzle: 3136 = 8 XCDs x 392 slots.
    const int id   = blockIdx.x;
    const int wg   = (id & 7) * 392 + (id >> 3);
    const int tile = wg % 49;
    const int pg   = wg / 49;                    // pg = b*16 + g
    const int g    = pg & 15;
    const int b    = pg >> 4;
    const int th = tile / 7, tw = tile % 7;
    const int h0 = th * 8, w0 = tw * 8;
    const int lane = t & 63, wvid = t >> 6;
    const int mrow = lane & 15, quad = lane >> 4;

    // ---- halo prefetch FIRST: 16ch x 14rows x 4 f4 (cols w0-4..w0+11) ----
    float4 rv4[4];
    int    rslot[4];
#pragma unroll
    for (int i = 0; i < 4; ++i) {
        int s = t + i * 256;
        rslot[i] = s;
        float4 v = make_float4(0.f, 0.f, 0.f, 0.f);
        if (s < 896) {
            int ch = s / 56, r = s % 56;
            int row = r >> 2, q = r & 3;
            int gh = h0 + row - 3;
            int gwb = w0 - 4 + q * 4;
            bool ok = (gh >= 0) & (gh < 56) & (gwb >= 0) & (gwb <= 52);
            int ghc = min(max(gh, 0), 55);
            int gwc = min(max(gwb, 0), 52);
            float4 ld = *(const float4*)&x[(size_t)(b * 256 + g * 16 + ch) * 3136 +
                                           ghc * 56 + gwc];
            if (ok) v = ld;
        }
        rv4[i] = v;
    }

    // A-fragments: cw f32 -> f16 inline (L2-hot); rows >=49 are zero
    const int krow = wvid * 16 + mrow;
    half8t a0 = {}, a1 = {};
    if (krow < 49) {
        const float* src = &cw[(size_t)(g * 49 + krow) * 64 + quad * 8];
        a0 = pack8(*(const float4*)src,        *(const float4*)(src + 4),  1.f);
        a1 = pack8(*(const float4*)(src + 32), *(const float4*)(src + 36), 1.f);
    }

    // stage lmid [px][c] (stride 72): contiguous-slot b128 copies
#pragma unroll
    for (int i = 0; i < 2; ++i) {
        int s  = t + i * 256;
        int px = s >> 3, c8 = s & 7;
        int pix = (h0 + (px >> 3)) * 56 + w0 + (px & 7);
        *(half8t*)&lmid[px * 72 + c8 * 8] =
            *(const half8t*)&mid[(size_t)(b * 3136 + pix) * 64 + c8 * 8];
    }
    __syncthreads();

    // MFMA GEMM: D[ko][px] = sum_c W[ko][c] * M[c][px] -> lw2h f16
    {
        float bias[4];
        int   kor[4];
#pragma unroll
        for (int i = 0; i < 4; ++i) {
            kor[i]  = wvid * 16 + quad * 4 + i;
            bias[i] = (kor[i] < 49) ? cb[g * 49 + kor[i]] : 0.f;
        }
#pragma unroll
        for (int pt = 0; pt < 4; ++pt) {
            half8t b0 = *(const half8t*)&lmid[(pt * 16 + mrow) * 72 + quad * 8];
            half8t b1 = *(const half8t*)&lmid[(pt * 16 + mrow) * 72 + quad * 8 + 32];
            floatx4 acc = {0.f, 0.f, 0.f, 0.f};
            acc = __builtin_amdgcn_mfma_f32_16x16x32_f16(a0, b0, acc, 0, 0, 0);
            acc = __builtin_amdgcn_mfma_f32_16x16x32_f16(a1, b1, acc, 0, 0, 0);
#pragma unroll
            for (int i = 0; i < 4; ++i)
                if (kor[i] < 49)
                    lw2h[kor[i] * 68 + pt * 16 + mrow] = (__fp16)(acc[i] + bias[i]);
        }
    }
    __syncthreads();

    // halo f4 regs -> lxh f16 [ch][row][20] (half4 stores)
#pragma unroll
    for (int i = 0; i < 4; ++i) {
        int s = rslot[i];
        if (s < 896) {
            int ch = s / 56, r = s % 56;
            int row = r >> 2, q = r & 3;
            half2t p0 = __builtin_amdgcn_cvt_pkrtz(rv4[i].x, rv4[i].y);
            half2t p1 = __builtin_amdgcn_cvt_pkrtz(rv4[i].z, rv4[i].w);
            half4t hv; hv[0] = p0[0]; hv[1] = p0[1]; hv[2] = p1[0]; hv[3] = p1[1];
            *(half4t*)&lxh[ch * 280 + row * 20 + q * 4] = hv;
        }
    }
    __syncthreads();

    // apply: thread = (cc = t>>4, 4 px); 3x half4 xr + half4 wq per (kh,kw)
    const int cc = t >> 4, pxt = t & 15;
    const int sh = pxt >> 1, sw4 = (pxt & 1) * 4;
    float a0f = 0.f, a1f = 0.f, a2f = 0.f, a3f = 0.f;
#pragma unroll
    for (int kh = 0; kh < 7; ++kh) {
        const int rbh = cc * 280 + (sh + kh) * 20 + sw4;
        half4t f0 = *(const half4t*)&lxh[rbh];
        half4t f1 = *(const half4t*)&lxh[rbh + 4];
        half4t f2 = *(const half4t*)&lxh[rbh + 8];
        float xw[12];
#pragma unroll
        for (int j = 0; j < 4; ++j) {
            xw[j]     = (float)f0[j];
            xw[j + 4] = (float)f1[j];
            xw[j + 8] = (float)f2[j];
        }
#pragma unroll
        for (int kw = 0; kw < 7; ++kw) {
            half4t wq = *(const half4t*)&lw2h[(kh * 7 + kw) * 68 + pxt * 4];
            a0f = fmaf((float)wq[0], xw[kw + 1], a0f);
            a1f = fmaf((float)wq[1], xw[kw + 2], a1f);
            a2f = fmaf((float)wq[2], xw[kw + 3], a2f);
            a3f = fmaf((float)wq[3], xw[kw + 4], a3f);
        }
    }
    *(float4*)&out[(size_t)(b * 256 + g * 16 + cc) * 3136 + (h0 + sh) * 56 + w0 + sw4] =
        make_float4(a0f, a1f, a2f, a3f);
}

extern "C" void kernel_launch(void* const* d_in, const int* in_sizes, int n_in,
                              void* d_out, int out_size, void* d_ws, size_t ws_size,
                              hipStream_t stream) {
    const float* x     = (const float*)d_in[0];
    const float* w1    = (const float*)d_in[1];
    const float* gamma = (const float*)d_in[2];
    const float* beta  = (const float*)d_in[3];
    const float* mean  = (const float*)d_in[4];
    const float* var   = (const float*)d_in[5];
    const float* cw    = (const float*)d_in[6];
    const float* cb    = (const float*)d_in[7];
    float* out = (float*)d_out;

    __fp16* mid = (__fp16*)d_ws;             // 1605632 B

    k1_conv1<<<dim3(98, 4), 256, 0, stream>>>(x, w1, gamma, beta, mean, var, mid);
    k23_fused<<<dim3(3136), 256, 0, stream>>>(x, mid, cw, cb, out);
}

// Round 13
// 100.525 us; speedup vs baseline: 1.0722x; 1.0220x over previous
//
#include <hip/hip_runtime.h>

// Involution: B=4, C=256, H=W=56, K=7, GC=16 -> G=16, Cr=64, K2=49
// R13: R12 base + two independent per-kernel changes:
//  k1: coalesced staging map (pxq in low lane bits -> 4-lane 64B bursts,
//      was 64 scattered lines/instr; LDS half2 writes stay 2-way-free).
//      [R5-verified correct; retried isolated]
//  k2: lw2 transposed to [pxt][kh][32] f16 stripes (232 halves/pxt, 2-way
//      bank-free b128 reads) -> apply weight reads 49 -> 28 instrs/wave.
// ws: mid f16 [4][3136 px][64 c] @0 (1605632 B).

#define EPS 1e-5f

typedef __fp16 half2t __attribute__((ext_vector_type(2)));
typedef __fp16 half4t __attribute__((ext_vector_type(4)));
typedef __fp16 half8t __attribute__((ext_vector_type(8)));
typedef float floatx4 __attribute__((ext_vector_type(4)));

__device__ inline half8t pack8(float4 u0, float4 u1, float s) {
    half8t a;
    half2t q;
    q = __builtin_amdgcn_cvt_pkrtz(u0.x * s, u0.y * s); a[0] = q[0]; a[1] = q[1];
    q = __builtin_amdgcn_cvt_pkrtz(u0.z * s, u0.w * s); a[2] = q[0]; a[3] = q[1];
    q = __builtin_amdgcn_cvt_pkrtz(u1.x * s, u1.y * s); a[4] = q[0]; a[5] = q[1];
    q = __builtin_amdgcn_cvt_pkrtz(u1.z * s, u1.w * s); a[6] = q[0]; a[7] = q[1];
    return a;
}

// ---------------- Kernel 1: conv1 (1x1, 256->64) + BN + ReLU, MFMA ----------
// grid (98,4): block 64o x 32px. Staging: thread = (ch-pair p, px-quad pxq),
// pxq in LOW lane bits -> 4-lane 64B contiguous global bursts. Loads hoisted.
__global__ __launch_bounds__(256, 4) void k1_conv1(
    const float* __restrict__ x, const float* __restrict__ w1,
    const float* __restrict__ gamma, const float* __restrict__ beta,
    const float* __restrict__ mean, const float* __restrict__ var,
    __fp16* __restrict__ mid)
{
    __shared__ __align__(16) __fp16 lxB[4 * 32 * 72];  // [chunk][px][72]
    const int t    = threadIdx.x;
    const int b    = blockIdx.y;
    const int p0   = blockIdx.x * 32;
    const int lane = t & 63, wvid = t >> 6;
    const int mrow = lane & 15, quad = lane >> 4;

    // staging map: pair p in 0..31, px-quad pxq in 0..7 (pxq in low bits)
    const int p   = (lane >> 2) + 16 * (wvid & 1);
    const int pxq = (lane & 3) + 4 * (wvid >> 1);

    // ---- all 4 chunks' loads in flight ----
    float4 ra[4], rb[4];
#pragma unroll
    for (int ch = 0; ch < 4; ++ch) {
        const float* r0 = &x[(size_t)(b * 256 + ch * 64 + 2 * p) * 3136 + p0 + pxq * 4];
        ra[ch] = *(const float4*)r0;
        rb[ch] = *(const float4*)(r0 + 3136);
    }

    // ---- A-fragments meanwhile: BN scale folded, f32 -> f16 (w1 L2-hot) ----
    const int orow = wvid * 16 + mrow;
    const float s = gamma[orow] * rsqrtf(var[orow] + EPS);
    half8t A[4][2];
#pragma unroll
    for (int ch = 0; ch < 4; ++ch)
#pragma unroll
        for (int h = 0; h < 2; ++h) {
            const float* src = &w1[orow * 256 + ch * 64 + h * 32 + quad * 8];
            A[ch][h] = pack8(*(const float4*)src, *(const float4*)(src + 4), s);
        }

    // ---- write all chunks to LDS (half2 ch-pairs), one barrier ----
#pragma unroll
    for (int ch = 0; ch < 4; ++ch) {
        const float* f0 = (const float*)&ra[ch];
        const float* f1 = (const float*)&rb[ch];
#pragma unroll
        for (int j = 0; j < 4; ++j) {
            half2t q = __builtin_amdgcn_cvt_pkrtz(f0[j], f1[j]);
            *(half2t*)&lxB[ch * 2304 + (pxq * 4 + j) * 72 + 2 * p] = q;
        }
    }
    __syncthreads();

    // ---- MFMA: 16 per wave, no intervening barriers ----
    floatx4 acc[2] = {};
#pragma unroll
    for (int ch = 0; ch < 4; ++ch)
#pragma unroll
        for (int pt = 0; pt < 2; ++pt) {
            half8t bf0 = *(const half8t*)&lxB[ch * 2304 + (pt * 16 + mrow) * 72 + quad * 8];
            half8t bf1 = *(const half8t*)&lxB[ch * 2304 + (pt * 16 + mrow) * 72 + quad * 8 + 32];
            acc[pt] = __builtin_amdgcn_mfma_f32_16x16x32_f16(A[ch][0], bf0, acc[pt], 0, 0, 0);
            acc[pt] = __builtin_amdgcn_mfma_f32_16x16x32_f16(A[ch][1], bf1, acc[pt], 0, 0, 0);
        }
    __syncthreads();

    // ---- epilogue: bias + relu -> f16, transpose via lxB, b128 out ----
    float bb[4];
#pragma unroll
    for (int i = 0; i < 4; ++i) {
        int o = wvid * 16 + quad * 4 + i;
        float so = gamma[o] * rsqrtf(var[o] + EPS);
        bb[i] = beta[o] - mean[o] * so;
    }
#pragma unroll
    for (int pt = 0; pt < 2; ++pt)
#pragma unroll
        for (int i = 0; i < 4; ++i) {
            float v = fmaxf(acc[pt][i] + bb[i], 0.f);
            lxB[(pt * 16 + mrow) * 72 + wvid * 16 + quad * 4 + i] = (__fp16)v;
        }
    __syncthreads();
    {
        int px = t >> 3, o8 = t & 7;                 // 256 slots = 32px x 8
        *(half8t*)&mid[(size_t)(b * 3136 + p0 + px) * 64 + o8 * 8] =
            *(const half8t*)&lxB[px * 72 + o8 * 8];
    }
}

// ---------------- Kernel 2: fused conv2 (f16 MFMA) + unfold/apply -----------
// grid: 3136 linear blocks, XCD-chunked swizzle.
// LDS map (bytes):
//   [0, 9216)      lmid [64px][72] f16        (GEMM phase only)
//   [0, 8960)      lxh  [16ch][14][20] f16    (halo, overlays lmid AFTER GEMM)
//   [9216, 16640)  lw2t [16pxt][232] f16      (weights, transposed stripes)
__global__ __launch_bounds__(256, 5) void k23_fused(
    const float* __restrict__ x, const __fp16* __restrict__ mid,
    const float* __restrict__ cw, const float* __restrict__ cb,
    float* __restrict__ out)
{
    __shared__ __align__(16) unsigned char smem[16640];
    __fp16* lmid = (__fp16*)smem;
    __fp16* lxh  = (__fp16*)smem;                // ch stride 280, row stride 20
    __fp16* lw2t = (__fp16*)(smem + 9216);       // [pxt][kh*32 + kw*4 + j]

    const int t  = threadIdx.x;
    // ---- XCD-chunked bijective swizzle: 3136 = 8 XCDs x 392 slots.
    const int id   = blockIdx.x;
    const int wg   = (id & 7) * 392 + (id >> 3);
    const int tile = wg % 49;
    const int pg   = wg / 49;                    // pg = b*16 + g
    const int g    = pg & 15;
    const int b    = pg >> 4;
    const int th = tile / 7, tw = tile % 7;
    const int h0 = th * 8, w0 = tw * 8;
    const int lane = t & 63, wvid = t >> 6;
    const int mrow = lane & 15, quad = lane >> 4;

    // ---- halo prefetch FIRST: 16ch x 14rows x 4 f4 (cols w0-4..w0+11) ----
    float4 rv4[4];
    int    rslot[4];
#pragma unroll
    for (int i = 0; i < 4; ++i) {
        int s = t + i * 256;
        rslot[i] = s;
        float4 v = make_float4(0.f, 0.f, 0.f, 0.f);
        if (s < 896) {
            int ch = s / 56, r = s % 56;
            int row = r >> 2, q = r & 3;
            int gh = h0 + row - 3;
            int gwb = w0 - 4 + q * 4;
            bool ok = (gh >= 0) & (gh < 56) & (gwb >= 0) & (gwb <= 52);
            int ghc = min(max(gh, 0), 55);
            int gwc = min(max(gwb, 0), 52);
            float4 ld = *(const float4*)&x[(size_t)(b * 256 + g * 16 + ch) * 3136 +
                                           ghc * 56 + gwc];
            if (ok) v = ld;
        }
        rv4[i] = v;
    }

    // A-fragments: cw f32 -> f16 inline (L2-hot); rows >=49 are zero
    const int krow = wvid * 16 + mrow;
    half8t a0 = {}, a1 = {};
    if (krow < 49) {
        const float* src = &cw[(size_t)(g * 49 + krow) * 64 + quad * 8];
        a0 = pack8(*(const float4*)src,        *(const float4*)(src + 4),  1.f);
        a1 = pack8(*(const float4*)(src + 32), *(const float4*)(src + 36), 1.f);
    }

    // stage lmid [px][c] (stride 72): contiguous-slot b128 copies
#pragma unroll
    for (int i = 0; i < 2; ++i) {
        int s  = t + i * 256;
        int px = s >> 3, c8 = s & 7;
        int pix = (h0 + (px >> 3)) * 56 + w0 + (px & 7);
        *(half8t*)&lmid[px * 72 + c8 * 8] =
            *(const half8t*)&mid[(size_t)(b * 3136 + pix) * 64 + c8 * 8];
    }
    __syncthreads();

    // MFMA GEMM: D[ko][px] -> lw2t f16 transposed stripes
    {
        float bias[4];
        int   kor[4], koh[4], kow[4];
#pragma unroll
        for (int i = 0; i < 4; ++i) {
            kor[i]  = wvid * 16 + quad * 4 + i;
            koh[i]  = kor[i] / 7;
            kow[i]  = kor[i] - 7 * koh[i];
            bias[i] = (kor[i] < 49) ? cb[g * 49 + kor[i]] : 0.f;
        }
#pragma unroll
        for (int pt = 0; pt < 4; ++pt) {
            half8t b0 = *(const half8t*)&lmid[(pt * 16 + mrow) * 72 + quad * 8];
            half8t b1 = *(const half8t*)&lmid[(pt * 16 + mrow) * 72 + quad * 8 + 32];
            floatx4 acc = {0.f, 0.f, 0.f, 0.f};
            acc = __builtin_amdgcn_mfma_f32_16x16x32_f16(a0, b0, acc, 0, 0, 0);
            acc = __builtin_amdgcn_mfma_f32_16x16x32_f16(a1, b1, acc, 0, 0, 0);
            // px = pt*16 + mrow; pxt = px>>2 = pt*4 + (mrow>>2); j = px&3
            const int pb = (pt * 4 + (mrow >> 2)) * 232 + (mrow & 3);
#pragma unroll
            for (int i = 0; i < 4; ++i)
                if (kor[i] < 49)
                    lw2t[pb + koh[i] * 32 + kow[i] * 4] = (__fp16)(acc[i] + bias[i]);
        }
    }
    __syncthreads();

    // halo f4 regs -> lxh f16 [ch][row][20] (half4 stores)
#pragma unroll
    for (int i = 0; i < 4; ++i) {
        int s = rslot[i];
        if (s < 896) {
            int ch = s / 56, r = s % 56;
            int row = r >> 2, q = r & 3;
            half2t p0 = __builtin_amdgcn_cvt_pkrtz(rv4[i].x, rv4[i].y);
            half2t p1 = __builtin_amdgcn_cvt_pkrtz(rv4[i].z, rv4[i].w);
            half4t hv; hv[0] = p0[0]; hv[1] = p0[1]; hv[2] = p1[0]; hv[3] = p1[1];
            *(half4t*)&lxh[ch * 280 + row * 20 + q * 4] = hv;
        }
    }
    __syncthreads();

    // apply: thread = (cc = t>>4, 4 px); per kh: 3x half4 xr + 4x half8 wq
    const int cc = t >> 4, pxt = t & 15;
    const int sh = pxt >> 1, sw4 = (pxt & 1) * 4;
    float a0f = 0.f, a1f = 0.f, a2f = 0.f, a3f = 0.f;
#pragma unroll
    for (int kh = 0; kh < 7; ++kh) {
        const int rbh = cc * 280 + (sh + kh) * 20 + sw4;
        half4t f0 = *(const half4t*)&lxh[rbh];
        half4t f1 = *(const half4t*)&lxh[rbh + 4];
        half4t f2 = *(const half4t*)&lxh[rbh + 8];
        float xw[12];
#pragma unroll
        for (int j = 0; j < 4; ++j) {
            xw[j]     = (float)f0[j];
            xw[j + 4] = (float)f1[j];
            xw[j + 8] = (float)f2[j];
        }
        const __fp16* wb = &lw2t[pxt * 232 + kh * 32];
        half8t wv0 = *(const half8t*)(wb);
        half8t wv1 = *(const half8t*)(wb + 8);
        half8t wv2 = *(const half8t*)(wb + 16);
        half8t wv3 = *(const half8t*)(wb + 24);
#pragma unroll
        for (int kw = 0; kw < 7; ++kw) {
            // wq[j] = stripe element kw*4+j, compile-time register lane
            __fp16 q0, q1, q2, q3;
            if (kw < 2)      { q0 = wv0[kw*4+0]; q1 = wv0[kw*4+1]; q2 = wv0[kw*4+2]; q3 = wv0[kw*4+3]; }
            else if (kw < 4) { q0 = wv1[(kw-2)*4+0]; q1 = wv1[(kw-2)*4+1]; q2 = wv1[(kw-2)*4+2]; q3 = wv1[(kw-2)*4+3]; }
            else if (kw < 6) { q0 = wv2[(kw-4)*4+0]; q1 = wv2[(kw-4)*4+1]; q2 = wv2[(kw-4)*4+2]; q3 = wv2[(kw-4)*4+3]; }
            else             { q0 = wv3[0]; q1 = wv3[1]; q2 = wv3[2]; q3 = wv3[3]; }
            a0f = fmaf((float)q0, xw[kw + 1], a0f);
            a1f = fmaf((float)q1, xw[kw + 2], a1f);
            a2f = fmaf((float)q2, xw[kw + 3], a2f);
            a3f = fmaf((float)q3, xw[kw + 4], a3f);
        }
    }
    *(float4*)&out[(size_t)(b * 256 + g * 16 + cc) * 3136 + (h0 + sh) * 56 + w0 + sw4] =
        make_float4(a0f, a1f, a2f, a3f);
}

extern "C" void kernel_launch(void* const* d_in, const int* in_sizes, int n_in,
                              void* d_out, int out_size, void* d_ws, size_t ws_size,
                              hipStream_t stream) {
    const float* x     = (const float*)d_in[0];
    const float* w1    = (const float*)d_in[1];
    const float* gamma = (const float*)d_in[2];
    const float* beta  = (const float*)d_in[3];
    const float* mean  = (const float*)d_in[4];
    const float* var   = (const float*)d_in[5];
    const float* cw    = (const float*)d_in[6];
    const float* cb    = (const float*)d_in[7];
    float* out = (float*)d_out;

    __fp16* mid = (__fp16*)d_ws;             // 1605632 B

    k1_conv1<<<dim3(98, 4), 256, 0, stream>>>(x, w1, gamma, beta, mean, var, mid);
    k23_fused<<<dim3(3136), 256, 0, stream>>>(x, mid, cw, cb, out);
}